// Round 4
// baseline (277.457 us; speedup 1.0000x reference)
//
#include <hip/hip_runtime.h>

// CRF forward-score + gold-score, MI355X (gfx950).
//
// R8: SINGLE-WAVE DUAL-CHAIN. R7 (2 waves: fwd chain + bwd chain) measured
// 126 us, VALUBusy 72%: per step each wave issues ~425 busy cyc but the
// window is 1180 cyc -- the per-step serial tail (z tree-reduce ->
// readlane z -> SALU exponent -> muls -> next broadcasts) is not fully
// covered by SMT between the 2 waves/SIMD. Chains/SIMD is pinned at 2
// (2048 chains / 1024 SIMDs), so switch from 2 waves x 1 chain to
// 1 wave x 2 chains: both chains of batch b run INTERLEAVED in one
// 64-thread wave. In-order issue alternates two independent dep graphs,
// so each chain's latency gaps are filled by the other chain's ready ops
// (ILP fill instead of SMT fill). Bonus: final contraction sum_l x_l*y_l
// is lane-local -> zero LDS, zero __syncthreads.
//
// Math (identical to verified R7, absmax 0.0):
//   1^T beta_511 = y^T x
//     x = prod_{t=1..255}  (D_t E)   beta_0        (fwd, 255 steps)
//     y = prod_{t=511..256}(E^T D_t) 1             (bwd, 256 steps)
// Joint loop runs 255 iterations (fwd t=1..255 with bwd t=511..257
// interleaved), then one bwd-only tail step (t=256). Per-chain op order
// and normalization order are exactly R7's.
//
// Exp-domain recurrence with fresh pow2 normalization (proven R4):
//   z = E * beta (readlane->SGPR broadcast + fmac), e = exponent(z[0]),
//   beta' = (z * exp(u)) * 2^-e, esum += e (exact int), applied once at
//   the end: fwd = log(sum x*y) + (esumA+esumB)*ln2.
// Sentinels: E row START = 0, E^T row STOP = 0 (fp32 underflow of -10000),
// consistent with the reference's own underflow.
//
// Both rings depth 5 (255 = 5*51); exp(u_next) computed one step early.
// VGPR: E(64) + E^T(64) + 4 acc float4(16) + rings(10) + misc ~= 170.
// __launch_bounds__(64,1) -> 1 wave/SIMD, cap ~512 VGPR, no spill
// (spill signature would be ~450 us, R1).

#define BB 1024
#define TT 512
#define KK 64
#define START_TAG 62

// broadcast lane l's float to all lanes via SGPR (l must be a literal 0..63)
#define RLF(v, l) __uint_as_float((unsigned)__builtin_amdgcn_readlane((int)__float_as_uint(v), (l)))

__global__ __launch_bounds__(64, 1) void crf_fused_kernel(
    const float* __restrict__ feats,   // [B, T, K]
    const int*   __restrict__ tags,    // [B, T]
    const float* __restrict__ trans,   // [K, K]  trans[i*K+j] = score j -> i
    float*       __restrict__ diff)    // [B]  forward - gold
{
  const int lane = threadIdx.x;        // 0..63 == tag index
  const int b    = blockIdx.x;

  // ---- E row (fwd): e4[jc] = exp(trans[lane][4jc..4jc+3]) ----
  float4 e4[16];
  {
    const float4* trow = (const float4*)(trans + lane * KK);
    #pragma unroll
    for (int jc = 0; jc < 16; ++jc) {
      float4 tv = trow[jc];
      e4[jc] = make_float4(__expf(tv.x), __expf(tv.y),
                           __expf(tv.z), __expf(tv.w));
    }
  }
  // ---- E^T row (bwd): et4[jc].m = exp(trans[(4jc+m)*K + lane]) ----
  float4 et4[16];
  #pragma unroll
  for (int jc = 0; jc < 16; ++jc) {
    et4[jc].x = __expf(trans[(4*jc + 0) * KK + lane]);
    et4[jc].y = __expf(trans[(4*jc + 1) * KK + lane]);
    et4[jc].z = __expf(trans[(4*jc + 2) * KK + lane]);
    et4[jc].w = __expf(trans[(4*jc + 3) * KK + lane]);
  }

  const float* fb = feats + (size_t)b * TT * KK + lane;

  // ---- prefetch rings, both depth 5 ----
  float upfA[5];                        // fwd: u_1..u_5
  float upfB[5];                        // bwd: u_511..u_507
  #pragma unroll
  for (int d = 0; d < 5; ++d) {
    upfA[d] = fb[(size_t)(1 + d) * KK];
    upfB[d] = fb[(size_t)(511 - d) * KK];
  }

  float beta = (lane == START_TAG) ? 1.0f : 0.0f;   // fwd state x
  float y    = 1.0f;                                 // bwd state
  int   esumA = 0, esumB = 0;
  float fA = __expf(upfA[0]);          // exp(u_1)
  float fB = __expf(upfB[0]);          // exp(u_511)

  for (int g = 0; g < 51; ++g) {
    #pragma unroll
    for (int d = 0; d < 5; ++d) {
      const int tA = 1 + g * 5 + d;    // 1..255
      const int tB = 511 - (g * 5 + d);// 511..257

      float w = y * fB;                // bwd applies f BEFORE E^T

      // interleaved dual matvec: zA = E*beta, zB = E^T*w
      float4 a0 = {0.f, 0.f, 0.f, 0.f};
      float4 a1 = {0.f, 0.f, 0.f, 0.f};
      float4 c0 = {0.f, 0.f, 0.f, 0.f};
      float4 c1 = {0.f, 0.f, 0.f, 0.f};
      #pragma unroll
      for (int jc = 0; jc < 16; jc += 2) {
        a0.x = fmaf(e4[jc].x,      RLF(beta, 4*jc + 0), a0.x);
        c0.x = fmaf(et4[jc].x,     RLF(w,    4*jc + 0), c0.x);
        a0.y = fmaf(e4[jc].y,      RLF(beta, 4*jc + 1), a0.y);
        c0.y = fmaf(et4[jc].y,     RLF(w,    4*jc + 1), c0.y);
        a0.z = fmaf(e4[jc].z,      RLF(beta, 4*jc + 2), a0.z);
        c0.z = fmaf(et4[jc].z,     RLF(w,    4*jc + 2), c0.z);
        a0.w = fmaf(e4[jc].w,      RLF(beta, 4*jc + 3), a0.w);
        c0.w = fmaf(et4[jc].w,     RLF(w,    4*jc + 3), c0.w);
        a1.x = fmaf(e4[jc + 1].x,  RLF(beta, 4*jc + 4), a1.x);
        c1.x = fmaf(et4[jc + 1].x, RLF(w,    4*jc + 4), c1.x);
        a1.y = fmaf(e4[jc + 1].y,  RLF(beta, 4*jc + 5), a1.y);
        c1.y = fmaf(et4[jc + 1].y, RLF(w,    4*jc + 5), c1.y);
        a1.z = fmaf(e4[jc + 1].z,  RLF(beta, 4*jc + 6), a1.z);
        c1.z = fmaf(et4[jc + 1].z, RLF(w,    4*jc + 6), c1.z);
        a1.w = fmaf(e4[jc + 1].w,  RLF(beta, 4*jc + 7), a1.w);
        c1.w = fmaf(et4[jc + 1].w, RLF(w,    4*jc + 7), c1.w);
      }
      float zA = ((a0.x + a1.x) + (a0.y + a1.y)) +
                 ((a0.z + a1.z) + (a0.w + a1.w));
      float zB = ((c0.x + c1.x) + (c0.y + c1.y)) +
                 ((c0.z + c1.z) + (c0.w + c1.w));

      // ring refills (clamped)
      int tnA = tA + 5; if (tnA > 255) tnA = 255;
      int tnB = tB - 5; if (tnB < 256) tnB = 256;
      upfA[d] = fb[(size_t)tnA * KK];
      upfB[d] = fb[(size_t)tnB * KK];

      // fresh pow2 normalization, exponent bookkeeping on SALU
      unsigned zbA = (unsigned)__builtin_amdgcn_readlane((int)__float_as_uint(zA), 0);
      unsigned zbB = (unsigned)__builtin_amdgcn_readlane((int)__float_as_uint(zB), 0);
      float sA = __uint_as_float(0x7F000000u - (zbA & 0x7F800000u)); // 2^-(e-127)
      float sB = __uint_as_float(0x7F000000u - (zbB & 0x7F800000u));
      esumA += (int)((zbA >> 23) & 0xFFu) - 127;
      esumB += (int)((zbB >> 23) & 0xFFu) - 127;
      beta = (zA * fA) * sA;
      y    = zB * sB;

      // next step's feat factors (off critical path)
      fA = __expf(upfA[(d + 1 < 5) ? d + 1 : 0]);
      fB = __expf(upfB[(d + 1 < 5) ? d + 1 : 0]);
    }
  }

  // ---- bwd tail step t = 256 (fB == exp(u_256) here) ----
  {
    float w = y * fB;
    float4 c0 = {0.f, 0.f, 0.f, 0.f};
    float4 c1 = {0.f, 0.f, 0.f, 0.f};
    #pragma unroll
    for (int jc = 0; jc < 16; jc += 2) {
      c0.x = fmaf(et4[jc].x,     RLF(w, 4*jc + 0), c0.x);
      c0.y = fmaf(et4[jc].y,     RLF(w, 4*jc + 1), c0.y);
      c0.z = fmaf(et4[jc].z,     RLF(w, 4*jc + 2), c0.z);
      c0.w = fmaf(et4[jc].w,     RLF(w, 4*jc + 3), c0.w);
      c1.x = fmaf(et4[jc + 1].x, RLF(w, 4*jc + 4), c1.x);
      c1.y = fmaf(et4[jc + 1].y, RLF(w, 4*jc + 5), c1.y);
      c1.z = fmaf(et4[jc + 1].z, RLF(w, 4*jc + 6), c1.z);
      c1.w = fmaf(et4[jc + 1].w, RLF(w, 4*jc + 7), c1.w);
    }
    float zB = ((c0.x + c1.x) + (c0.y + c1.y)) +
               ((c0.z + c1.z) + (c0.w + c1.w));
    unsigned zbB = (unsigned)__builtin_amdgcn_readlane((int)__float_as_uint(zB), 0);
    float sB = __uint_as_float(0x7F000000u - (zbB & 0x7F800000u));
    esumB += (int)((zbB >> 23) & 0xFFu) - 127;
    y = zB * sB;
  }

  // ---- forward score: log(sum_l x_l * y_l) + (esumA+esumB)*ln2 ----
  float p = beta * y;
  #pragma unroll
  for (int off = 32; off; off >>= 1) p += __shfl_xor(p, off);
  float fwd = __logf(p) + (float)(esumA + esumB) * 0.6931471805599453f;

  // ---- gold path score ----
  const int* tg = tags + b * TT;
  float gs = 0.0f;
  for (int tt = 1 + lane; tt < TT; tt += 64) {
    int tc = tg[tt];
    int tp = tg[tt - 1];
    gs += trans[tc * KK + tp]
        + feats[(size_t)b * TT * KK + (size_t)tt * KK + tc];
  }
  #pragma unroll
  for (int off = 32; off; off >>= 1) gs += __shfl_xor(gs, off);

  if (lane == 0) diff[b] = fwd - gs;
}

__global__ __launch_bounds__(1024) void reduce_mean_kernel(
    const float* __restrict__ diff, float* __restrict__ out)
{
  __shared__ float part[16];
  const int tid = threadIdx.x;
  float v = diff[tid];
  #pragma unroll
  for (int off = 32; off; off >>= 1) v += __shfl_xor(v, off);
  if ((tid & 63) == 0) part[tid >> 6] = v;
  __syncthreads();
  if (tid < 16) {
    float s = part[tid];
    #pragma unroll
    for (int off = 8; off; off >>= 1) s += __shfl_xor(s, off);
    if (tid == 0) out[0] = s * (1.0f / 1024.0f);
  }
}

extern "C" void kernel_launch(void* const* d_in, const int* in_sizes, int n_in,
                              void* d_out, int out_size, void* d_ws, size_t ws_size,
                              hipStream_t stream) {
  const float* feats = (const float*)d_in[0];
  const int*   tags  = (const int*)d_in[1];
  const float* trans = (const float*)d_in[2];
  float* out  = (float*)d_out;
  float* diff = (float*)d_ws;   // 1024 floats of scratch

  crf_fused_kernel<<<dim3(BB), dim3(64), 0, stream>>>(feats, tags, trans, diff);
  reduce_mean_kernel<<<dim3(1), dim3(1024), 0, stream>>>(diff, out);
}

// Round 5
// 253.703 us; speedup vs baseline: 1.0936x; 1.0936x over previous
//
#include <hip/hip_runtime.h>

// CRF forward-score + gold-score, MI355X (gfx950).
//
// R9: XOR-DPP BROADCAST. R8 showed the wave is ISSUE-bound: per chain-step
// ~425 busy cyc = 64 v_readlane(4cyc) + 64 v_fmac(2cyc) + misc. The
// readlane broadcast is 60% of issue. Replace it entirely:
//   z_i = sum_j E[i][j] b_j = sum_{m=0..63} E[i][i^m] * b_{i^m}
// b_{i^m} is built from pure XOR lane-permutations, all on the VALU pipe:
//   bits 0..1 : quad_perm [1,0,3,2]/[2,3,0,1]/[3,2,1,0]  (xor 1/2/3)
//               -- FUSED into v_fmac_f32_dpp, zero extra instructions
//   bits 0..3 : row_half_mirror (xor7), row_ror:8 (xor8), row_mirror
//               (xor15) as 12 v_mov_dpp copies per step
//   bits 4..5 : __shfl_xor 16/32/48 (3 ops, DS pipe, overlapped)
// Every permutation is an involution => DPP read-direction ambiguity
// cannot produce a wrong answer. E is loaded once in the matching
// diagonal layout et[m](lane) = exp(trans-element for (lane, lane^m)).
// Per-step issue drops ~425 -> ~190 cyc.
//
// HAZARD (why the nop fence exists): VALU-write -> DPP-read of the same
// VGPR needs 2 wait states on gfx9-lineage; the compiler cannot see that
// our inline-asm fmacs are DPP readers of the just-built copies. Fence:
// sched_barrier(0); s_nop 1; sched_barrier(0) between copy block and
// fmac block guarantees >=2 cycles regardless of scheduling.
//
// Structure = R7 (best measured, 126 us, absmax 0.0): 2 waves per block,
// wave0 fwd chain t=1..255, wave1 bwd chain t=511..256 (linear recurrence
// split: score = y^T x), fresh pow2 normalization with exact int exponent
// accumulators, rings depth 5 (fwd) / 4 (bwd), LDS handoff of y/esum/gold.
// __launch_bounds__(128,2): 2 waves/EU, VGPR cap 256 (need ~115).

#define BB 1024
#define TT 512
#define KK 64
#define START_TAG 62

// one-off readlane (z normalization only)
#define RL0(v) ((unsigned)__builtin_amdgcn_readlane((int)__float_as_uint(v), 0))

// v_mov_b32 dpp via update_dpp (compiler manages its own read hazards)
#define DPPX(src, ctrl) __uint_as_float((unsigned)__builtin_amdgcn_update_dpp( \
    0, (int)__float_as_uint(src), (ctrl), 0xF, 0xF, true))
#define CTL_HM  0x141   // row_half_mirror : xor 7
#define CTL_R8  0x128   // row_ror:8      : xor 8
#define CTL_MIR 0x140   // row_mirror     : xor 15

// fused fmac with quad_perm DPP on src0 (the beta copy)
#define FMQP1(acc, b, e) asm("v_fmac_f32_dpp %0, %1, %2 quad_perm:[1,0,3,2] row_mask:0xf bank_mask:0xf" : "+v"(acc) : "v"(b), "v"(e))
#define FMQP2(acc, b, e) asm("v_fmac_f32_dpp %0, %1, %2 quad_perm:[2,3,0,1] row_mask:0xf bank_mask:0xf" : "+v"(acc) : "v"(b), "v"(e))
#define FMQP3(acc, b, e) asm("v_fmac_f32_dpp %0, %1, %2 quad_perm:[3,2,1,0] row_mask:0xf bank_mask:0xf" : "+v"(acc) : "v"(b), "v"(e))

// z = sum_j E[.][j] b_j with E pre-arranged as et[T], T=(X<<4)|(bi<<2)|q,
// matching value b[lane ^ (16X ^ {0,7,8,15}[bi] ^ q)].
__device__ __forceinline__ float xdot64(float bv, const float (&et)[64]) {
  float cb00 = bv;
  float cb10 = __shfl_xor(bv, 16);
  float cb20 = __shfl_xor(bv, 32);
  float cb30 = __shfl_xor(bv, 48);
  float cb01 = DPPX(cb00, CTL_HM), cb02 = DPPX(cb00, CTL_R8), cb03 = DPPX(cb00, CTL_MIR);
  float cb11 = DPPX(cb10, CTL_HM), cb12 = DPPX(cb10, CTL_R8), cb13 = DPPX(cb10, CTL_MIR);
  float cb21 = DPPX(cb20, CTL_HM), cb22 = DPPX(cb20, CTL_R8), cb23 = DPPX(cb20, CTL_MIR);
  float cb31 = DPPX(cb30, CTL_HM), cb32 = DPPX(cb30, CTL_R8), cb33 = DPPX(cb30, CTL_MIR);
  float a0=0.f,a1=0.f,a2=0.f,a3=0.f,a4=0.f,a5=0.f,a6=0.f,a7=0.f;
  __builtin_amdgcn_sched_barrier(0);
  asm volatile("s_nop 1");
  __builtin_amdgcn_sched_barrier(0);
  // X = 0
  a0 = fmaf(cb00, et[ 0], a0); FMQP1(a1, cb00, et[ 1]); FMQP2(a2, cb00, et[ 2]); FMQP3(a3, cb00, et[ 3]);
  a4 = fmaf(cb01, et[ 4], a4); FMQP1(a5, cb01, et[ 5]); FMQP2(a6, cb01, et[ 6]); FMQP3(a7, cb01, et[ 7]);
  a0 = fmaf(cb02, et[ 8], a0); FMQP1(a1, cb02, et[ 9]); FMQP2(a2, cb02, et[10]); FMQP3(a3, cb02, et[11]);
  a4 = fmaf(cb03, et[12], a4); FMQP1(a5, cb03, et[13]); FMQP2(a6, cb03, et[14]); FMQP3(a7, cb03, et[15]);
  // X = 1
  a0 = fmaf(cb10, et[16], a0); FMQP1(a1, cb10, et[17]); FMQP2(a2, cb10, et[18]); FMQP3(a3, cb10, et[19]);
  a4 = fmaf(cb11, et[20], a4); FMQP1(a5, cb11, et[21]); FMQP2(a6, cb11, et[22]); FMQP3(a7, cb11, et[23]);
  a0 = fmaf(cb12, et[24], a0); FMQP1(a1, cb12, et[25]); FMQP2(a2, cb12, et[26]); FMQP3(a3, cb12, et[27]);
  a4 = fmaf(cb13, et[28], a4); FMQP1(a5, cb13, et[29]); FMQP2(a6, cb13, et[30]); FMQP3(a7, cb13, et[31]);
  // X = 2
  a0 = fmaf(cb20, et[32], a0); FMQP1(a1, cb20, et[33]); FMQP2(a2, cb20, et[34]); FMQP3(a3, cb20, et[35]);
  a4 = fmaf(cb21, et[36], a4); FMQP1(a5, cb21, et[37]); FMQP2(a6, cb21, et[38]); FMQP3(a7, cb21, et[39]);
  a0 = fmaf(cb22, et[40], a0); FMQP1(a1, cb22, et[41]); FMQP2(a2, cb22, et[42]); FMQP3(a3, cb22, et[43]);
  a4 = fmaf(cb23, et[44], a4); FMQP1(a5, cb23, et[45]); FMQP2(a6, cb23, et[46]); FMQP3(a7, cb23, et[47]);
  // X = 3
  a0 = fmaf(cb30, et[48], a0); FMQP1(a1, cb30, et[49]); FMQP2(a2, cb30, et[50]); FMQP3(a3, cb30, et[51]);
  a4 = fmaf(cb31, et[52], a4); FMQP1(a5, cb31, et[53]); FMQP2(a6, cb31, et[54]); FMQP3(a7, cb31, et[55]);
  a0 = fmaf(cb32, et[56], a0); FMQP1(a1, cb32, et[57]); FMQP2(a2, cb32, et[58]); FMQP3(a3, cb32, et[59]);
  a4 = fmaf(cb33, et[60], a4); FMQP1(a5, cb33, et[61]); FMQP2(a6, cb33, et[62]); FMQP3(a7, cb33, et[63]);
  return ((a0 + a4) + (a1 + a5)) + ((a2 + a6) + (a3 + a7));
}

__global__ __launch_bounds__(128, 2) void crf_dpp_kernel(
    const float* __restrict__ feats,   // [B, T, K]
    const int*   __restrict__ tags,    // [B, T]
    const float* __restrict__ trans,   // [K, K]  trans[i*K+j] = score j -> i
    float*       __restrict__ diff)    // [B]  forward - gold
{
  const int lane = threadIdx.x & 63;   // 0..63 == tag index
  const int wv   = threadIdx.x >> 6;   // 0 = forward chain, 1 = backward
  const int b    = blockIdx.x;

  __shared__ float ysh[KK];
  __shared__ float gs_sh;
  __shared__ int   esumB_sh;

  const float* fb = feats + (size_t)b * TT * KK + lane;
  const int Bv[4] = {0, 7, 8, 15};

  float beta = 0.0f;                   // wave0's final forward component
  int   esumA = 0;

  if (wv == 0) {
    // E in diagonal-XOR layout: et[T] = exp(E[lane][lane^m]), m=16X^Bv^q
    float et[64];
    #pragma unroll
    for (int T = 0; T < 64; ++T) {
      const int m = ((T >> 4) << 4) ^ Bv[(T >> 2) & 3] ^ (T & 3);
      et[T] = __expf(trans[lane * KK + (lane ^ m)]);
    }

    float upf[5];
    #pragma unroll
    for (int d = 0; d < 5; ++d) upf[d] = fb[(size_t)(1 + d) * KK];

    beta = (lane == START_TAG) ? 1.0f : 0.0f;
    float fA = __expf(upf[0]);         // exp(u_1)

    for (int g = 0; g < 51; ++g) {
      #pragma unroll
      for (int d = 0; d < 5; ++d) {
        const int t = 1 + g * 5 + d;   // 1..255

        float zA = xdot64(beta, et);

        int tn = t + 5; if (tn > 255) tn = 255;
        upf[d] = fb[(size_t)tn * KK];

        unsigned zb = RL0(zA);
        float s = __uint_as_float(0x7F000000u - (zb & 0x7F800000u)); // 2^-(e-127)
        esumA += (int)((zb >> 23) & 0xFFu) - 127;
        beta = (zA * fA) * s;

        fA = __expf(upf[(d + 1 < 5) ? d + 1 : 0]);
      }
    }
  } else {
    // E^T in diagonal-XOR layout: et[T] = exp(E[lane^m][lane])
    float et[64];
    #pragma unroll
    for (int T = 0; T < 64; ++T) {
      const int m = ((T >> 4) << 4) ^ Bv[(T >> 2) & 3] ^ (T & 3);
      et[T] = __expf(trans[(lane ^ m) * KK + lane]);
    }

    float upf[4];
    #pragma unroll
    for (int d = 0; d < 4; ++d) upf[d] = fb[(size_t)(511 - d) * KK];

    float y = 1.0f;
    int esum = 0;
    float fB = __expf(upf[0]);         // exp(u_511)

    for (int g = 0; g < 64; ++g) {
      #pragma unroll
      for (int d = 0; d < 4; ++d) {
        const int t = 511 - (g * 4 + d);   // 511..256

        float w = y * fB;                  // bwd applies f BEFORE E^T
        float zB = xdot64(w, et);

        int tn = t - 4; if (tn < 256) tn = 256;
        upf[d] = fb[(size_t)tn * KK];

        unsigned zb = RL0(zB);
        float s = __uint_as_float(0x7F000000u - (zb & 0x7F800000u));
        esum += (int)((zb >> 23) & 0xFFu) - 127;
        y = zB * s;

        fB = __expf(upf[(d + 1) & 3]);
      }
    }

    ysh[lane] = y;
    if (lane == 0) esumB_sh = esum;

    // ---- gold path score (on the backward wave) ----
    const int* tg = tags + b * TT;
    float gs = 0.0f;
    for (int tt = 1 + lane; tt < TT; tt += 64) {
      int tc = tg[tt];
      int tp = tg[tt - 1];
      gs += trans[tc * KK + tp]
          + feats[(size_t)b * TT * KK + (size_t)tt * KK + tc];
    }
    #pragma unroll
    for (int off = 32; off; off >>= 1) gs += __shfl_xor(gs, off);
    if (lane == 0) gs_sh = gs;
  }

  __syncthreads();

  if (wv == 0) {
    // forward score = log(x . y) + (esumA+esumB)*ln2
    float p = beta * ysh[lane];
    #pragma unroll
    for (int off = 32; off; off >>= 1) p += __shfl_xor(p, off);
    float fwd = __logf(p) + (float)(esumA + esumB_sh) * 0.6931471805599453f;
    if (lane == 0) diff[b] = fwd - gs_sh;
  }
}

__global__ __launch_bounds__(1024) void reduce_mean_kernel(
    const float* __restrict__ diff, float* __restrict__ out)
{
  __shared__ float part[16];
  const int tid = threadIdx.x;
  float v = diff[tid];
  #pragma unroll
  for (int off = 32; off; off >>= 1) v += __shfl_xor(v, off);
  if ((tid & 63) == 0) part[tid >> 6] = v;
  __syncthreads();
  if (tid < 16) {
    float s = part[tid];
    #pragma unroll
    for (int off = 8; off; off >>= 1) s += __shfl_xor(s, off);
    if (tid == 0) out[0] = s * (1.0f / 1024.0f);
  }
}

extern "C" void kernel_launch(void* const* d_in, const int* in_sizes, int n_in,
                              void* d_out, int out_size, void* d_ws, size_t ws_size,
                              hipStream_t stream) {
  const float* feats = (const float*)d_in[0];
  const int*   tags  = (const int*)d_in[1];
  const float* trans = (const float*)d_in[2];
  float* out  = (float*)d_out;
  float* diff = (float*)d_ws;   // 1024 floats of scratch

  crf_dpp_kernel<<<dim3(BB), dim3(128), 0, stream>>>(feats, tags, trans, diff);
  reduce_mean_kernel<<<dim3(1), dim3(1024), 0, stream>>>(diff, out);
}